// Round 1
// baseline (131.616 us; speedup 1.0000x reference)
//
#include <hip/hip_runtime.h>
#include <math.h>

#define NTGT 2048
#define NCLS 25
#define CHN  30

// cells per scale: 64*3*13*13 = 32448 ; 64*3*26*26 = 129792 ; 64*3*52*52 = 519168
#define OFF0 0
#define OFF1 32448
#define OFF2 162240
#define TOTAL_CELLS 681408

__constant__ float c_aw[3][3] = {{116.f,156.f,373.f},{30.f,62.f,59.f},{10.f,16.f,33.f}};
__constant__ float c_ah[3][3] = {{90.f,198.f,326.f},{61.f,45.f,119.f},{13.f,30.f,23.f}};
__constant__ int   c_g[3]     = {13, 26, 52};
__constant__ int   c_off[3]   = {OFF0, OFF1, OFF2};

// stable softplus == bce(x, 0) == -log_sigmoid(-x)
__device__ __forceinline__ float sp(float x) {
    return fmaxf(x, 0.f) + log1pf(expf(-fabsf(x)));
}

// Compute best anchor + cell linear index for target n at scale s.
__device__ __forceinline__ void target_cell(const float* __restrict__ tgt, int n, int s,
                                            int& cell, int& best,
                                            float& tx_, float& ty_, float& tw_, float& th_) {
    float bi_f = tgt[n*6+0];
    float x = tgt[n*6+2], y = tgt[n*6+3], w = tgt[n*6+4], h = tgt[n*6+5];
    int   gi = c_g[s];
    float g  = (float)gi;
    tx_ = x*g; ty_ = y*g; tw_ = w*g; th_ = h*g;
    int gx = (int)floorf(tx_);
    int gy = (int)floorf(ty_);
    float area = tw_*th_;
    best = 0;
    float bestiou = -1.f;
    #pragma unroll
    for (int k = 0; k < 3; ++k) {
        float sw = c_aw[s][k] / g, sh = c_ah[s][k] / g;
        float inter = fminf(tw_, sw) * fminf(th_, sh);
        float uni   = area + sw*sh - inter;
        float iou   = inter / (uni + 1e-9f);
        if (iou > bestiou) { bestiou = iou; best = k; }  // first-max wins (argmax semantics)
    }
    int bi = (int)bi_f;
    cell = ((bi*3 + best)*gi + gy)*gi + gx;
}

// Kernel 1: per-cell winner = max target index (matches numpy last-write-wins).
__global__ void scatter_k(const float* __restrict__ tgt, int* __restrict__ cellT) {
    int n = blockIdx.x * blockDim.x + threadIdx.x;
    if (n >= NTGT) return;
    #pragma unroll
    for (int s = 0; s < 3; ++s) {
        int cell, best; float tx_, ty_, tw_, th_;
        target_cell(tgt, n, s, cell, best, tx_, ty_, tw_, th_);
        atomicMax(&cellT[c_off[s] + cell], n);
    }
}

__device__ __forceinline__ float block_reduce(float v, float* smem) {
    #pragma unroll
    for (int o = 32; o > 0; o >>= 1) v += __shfl_down(v, o, 64);
    int lane = threadIdx.x & 63, wid = threadIdx.x >> 6;
    __syncthreads();                 // protect smem reuse across calls
    if (lane == 0) smem[wid] = v;
    __syncthreads();
    float t = 0.f;
    if (threadIdx.x == 0) {
        int nw = (int)(blockDim.x >> 6);
        for (int i = 0; i < nw; ++i) t += smem[i];
    }
    return t;
}

// Kernel 2: dense 0.5 * sum softplus(po) over ALL cells (channel 4 only).
__global__ void noobj_k(const float* __restrict__ pL, const float* __restrict__ pM,
                        const float* __restrict__ pS, float* __restrict__ out) {
    __shared__ float smem[4];
    float acc = 0.f;
    int stride = gridDim.x * blockDim.x;
    for (int e = blockIdx.x * blockDim.x + threadIdx.x; e < TOTAL_CELLS; e += stride) {
        const float* p; int local;
        if (e < OFF1)      { p = pL; local = e; }
        else if (e < OFF2) { p = pM; local = e - OFF1; }
        else               { p = pS; local = e - OFF2; }
        acc += sp(p[local*CHN + 4]);
    }
    float bsum = block_reduce(acc, smem);
    if (threadIdx.x == 0) {
        atomicAdd(&out[2], 0.5f * bsum);   // obj (noobj part, LAMBDA_NOOBJ)
        atomicAdd(&out[0], 0.5f * bsum);   // total
    }
}

// Kernel 3: sparse corrections at winning obj cells.
__global__ void corr_k(const float* __restrict__ pL, const float* __restrict__ pM,
                       const float* __restrict__ pS, const float* __restrict__ tgt,
                       const int* __restrict__ cellT, float* __restrict__ out) {
    __shared__ float smem[4];
    int tid = blockIdx.x * blockDim.x + threadIdx.x;   // [0, 3*NTGT)
    int s = tid / NTGT;        // wave-uniform (NTGT % 256 == 0)
    int n = tid % NTGT;
    float box = 0.f, objc = 0.f, cls = 0.f;
    if (tid < 3 * NTGT) {
        int cell, best; float tx_, ty_, tw_, th_;
        target_cell(tgt, n, s, cell, best, tx_, ty_, tw_, th_);
        if (cellT[c_off[s] + cell] == n) {   // this target won the cell
            const float* base = (s == 0 ? pL : (s == 1 ? pM : pS)) + (long)cell * CHN;
            float g  = (float)c_g[s];
            float tx = tx_ - floorf(tx_);
            float ty = ty_ - floorf(ty_);
            float sw = c_aw[s][best] / g, sh = c_ah[s][best] / g;
            float twl = logf(tw_ / sw + 1e-16f);
            float thl = logf(th_ / sh + 1e-16f);
            float px = base[0], py = base[1], pw = base[2], ph = base[3], po = base[4];
            box = (sp(px) - tx*px) + (sp(py) - ty*py)
                + (pw - twl)*(pw - twl) + (ph - thl)*(ph - thl);
            objc = sp(-po) - 0.5f * sp(po);  // replace noobj contrib with obj contrib
            int cid = (int)tgt[n*6+1];
            float cs = 0.f;
            #pragma unroll
            for (int c = 0; c < NCLS; ++c) cs += sp(base[5 + c]);
            cls = cs - base[5 + cid];        // softplus(-x) = softplus(x) - x
        }
    }
    float Sbox  = block_reduce(box,  smem);
    float Sobjc = block_reduce(objc, smem);
    float Scls  = block_reduce(cls,  smem);
    if (threadIdx.x == 0) {
        float b = 5.f * Sbox;                // LAMBDA_COORD
        atomicAdd(&out[1], b);
        atomicAdd(&out[2], Sobjc);
        atomicAdd(&out[3], Scls);            // LAMBDA_CLASS = 1
        atomicAdd(&out[0], b + Sobjc + Scls);
    }
}

extern "C" void kernel_launch(void* const* d_in, const int* in_sizes, int n_in,
                              void* d_out, int out_size, void* d_ws, size_t ws_size,
                              hipStream_t stream) {
    const float* pL  = (const float*)d_in[0];
    const float* pM  = (const float*)d_in[1];
    const float* pS  = (const float*)d_in[2];
    const float* tgt = (const float*)d_in[3];
    float* out = (float*)d_out;
    int* cellT = (int*)d_ws;   // TOTAL_CELLS ints = 2.73 MB

    hipMemsetAsync(out, 0, 4 * sizeof(float), stream);
    hipMemsetAsync(cellT, 0xFF, TOTAL_CELLS * sizeof(int), stream);  // -1
    scatter_k<<<NTGT / 256, 256, 0, stream>>>(tgt, cellT);
    noobj_k<<<512, 256, 0, stream>>>(pL, pM, pS, out);
    corr_k<<<(3 * NTGT + 255) / 256, 256, 0, stream>>>(pL, pM, pS, tgt, cellT, out);
}